// Round 1
// baseline (160.756 us; speedup 1.0000x reference)
//
#include <hip/hip_runtime.h>
#include <hip/hip_fp16.h>
#include <climits>

// Radon forward projection (parallel beam), 512x512 image, 512 angles,
// 736 detectors x 736 samples, bilinear interpolation.
// Outputs (flat, concatenated): sino [1,512,736] then reco [1,512,512].
//
// R13: proj_quad is VALU-issue-bound (VALUBusy 82%, HBM 2%). pk_*_f32 ops
//      are 4-cyc on SIMD32, so the 4 clamp ops were 16/80 cy of the inner
//      pair body -- but clamps are only needed as the out-of-own-range lane
//      MASK. Split each z-chunk into [head | clamp-free interior | tail]:
//      interior = wave-INTERSECTION of per-lane ranges computed with a
//      1e-3 margin (addressing provably safe unclamped); head/tail stay on
//      a scalar clamped path. Also: quads now store (l, r-l) so the
//      per-sample pk_sub_f16 moves into prep; one cvt_pkrtz for the fx
//      pair instead of two. Interior: 80 -> 62 cy/pair (predict -20% proj).

namespace {
constexpr int H = 512, W = 512, NA = 512, ND = 736, NS = 736;
constexpr int SINO_SIZE = NA * ND;
constexpr int IMG_SIZE = H * W;
// Quad array: entry (ri,ci), ri,ci in [0,513]:
//   q.x = (v(ri-1,ci-1), v(ri,ci-1))       column pair at ci-1  ("l")
//   q.y = (v(ri-1,ci)-v(ri-1,ci-1),
//          v(ri,ci)  -v(ri,ci-1))          delta pair ("r-l"), f32-computed
// zero outside [0,512)^2. Sample coords shifted +1 -> clamp domain [0,513].
constexpr int QN = 514;
constexpr int QS = 520;                 // row stride in quads (8 B each)
constexpr int QUAD_SIZE = QN * QS;
constexpr int KSPLIT = 8;
}

typedef __fp16 h2 __attribute__((ext_vector_type(2)));
typedef float  f2 __attribute__((ext_vector_type(2)));

// ---------- prep: quads + reco + sino zero; grid (17,17,4), block 32x8 -----
__global__ __launch_bounds__(256) void prep_quads(const float* __restrict__ x,
                                                  const float* __restrict__ reco,
                                                  uint2* __restrict__ Q,
                                                  uint2* __restrict__ QT,
                                                  float* __restrict__ reco_out,
                                                  float* __restrict__ sino) {
    __shared__ float tile[34][35];
    const int tx = threadIdx.x, ty = threadIdx.y;      // 32x8
    const int r0 = blockIdx.y * 32, c0 = blockIdx.x * 32;
    const int z  = blockIdx.z;

    // Zero sinogram (z==0 slice only; d_out is poisoned before every call).
    if (z == 0) {
        const int nthr = 289 * 256;
        const int gtid = (blockIdx.y * 17 + blockIdx.x) * 256 + ty * 32 + tx;
        for (int i = gtid; i < SINO_SIZE; i += nthr) sino[i] = 0.f;
    }

    // Load 34x34 halo tile: cell (yy,xx) = v(r0-1+yy, c0-1+xx), 0 outside.
    for (int li = ty * 32 + tx; li < 34 * 34; li += 256) {
        const int yy = li / 34, xx = li - yy * 34;
        const int r = r0 - 1 + yy, c = c0 - 1 + xx;
        float v = 0.f;
        if ((unsigned)r < 512u && (unsigned)c < 512u) {
            const int i = r * W + c;
            v = x[i] + reco[i];
        }
        tile[yy][xx] = v;
    }
    __syncthreads();

    const int t2 = ty + 8 * z;
    // Q quad: l = column pair at ci-1, delta = (col ci) - (col ci-1)
    const int ri = r0 + t2, ci = c0 + tx;
    if (ri < QN && ci < QN) {
        uint2 q;
        q.x = __builtin_bit_cast(unsigned int,
              __builtin_amdgcn_cvt_pkrtz(tile[t2][tx],     tile[t2 + 1][tx]));
        q.y = __builtin_bit_cast(unsigned int,
              __builtin_amdgcn_cvt_pkrtz(tile[t2][tx + 1]     - tile[t2][tx],
                                         tile[t2 + 1][tx + 1] - tile[t2 + 1][tx]));
        Q[ri * QS + ci] = q;
    }
    // Transposed-image quad at transposed block location.
    const int ri2 = c0 + t2, ci2 = r0 + tx;
    if (ri2 < QN && ci2 < QN) {
        uint2 q;
        q.x = __builtin_bit_cast(unsigned int,
              __builtin_amdgcn_cvt_pkrtz(tile[tx][t2],     tile[tx][t2 + 1]));
        q.y = __builtin_bit_cast(unsigned int,
              __builtin_amdgcn_cvt_pkrtz(tile[tx + 1][t2]     - tile[tx][t2],
                                         tile[tx + 1][t2 + 1] - tile[tx][t2 + 1]));
        QT[ri2 * QS + ci2] = q;
    }
    // reco pass-through (coalesced 4B/lane)
    const int rr = r0 + t2, cc = c0 + tx;
    if (rr < H && cc < W) reco_out[rr * W + cc] = reco[rr * W + cc];
}

// Per-dim k-range for p0 + k*inc in [lo, hi].
__device__ inline void range1(float p0, float inc, float lo, float hi,
                              float& klo, float& khi) {
    if (inc > 1e-6f)       { klo = (lo - p0) / inc; khi = (hi - p0) / inc; }
    else if (inc < -1e-6f) { klo = (hi - p0) / inc; khi = (lo - p0) / inc; }
    else if (p0 >= lo && p0 <= hi) { klo = -1e9f; khi = 1e9f; }
    else                   { klo = 1e9f;  khi = -1e9f; }
}

// Scalar clamped sample: clamp-to-[0,513] doubles as the out-of-own-range
// mask (clamped boundary quads are zero / zero-weighted by construction).
__device__ __forceinline__ void samp_clamped(const uint2* __restrict__ base,
                                             float F1, float S1, float fi, float sl,
                                             int j, float& acc) {
    const float jf = (float)j;
    float pf = fmaf(jf, fi, F1);
    float ps = fmaf(jf, sl, S1);
    pf = fminf(fmaxf(pf, 0.f), 513.f);
    ps = fminf(fmaxf(ps, 0.f), 513.f);
    const float ff = floorf(pf), sf = floorf(ps);
    const float fx = pf - ff,   fy = ps - sf;
    const unsigned ai = (unsigned)fmaf(sf, 520.f, ff);
    const uint2 q = base[ai];
    const h2 l  = __builtin_bit_cast(h2, q.x);
    const h2 dl = __builtin_bit_cast(h2, q.y);          // r - l (prep-computed)
    const h2 fxx = __builtin_amdgcn_cvt_pkrtz(fx, fx);
    const h2 m = fxx * dl + l;
    const h2 wy = __builtin_amdgcn_cvt_pkrtz(1.f - fy, fy);
#if __has_builtin(__builtin_amdgcn_fdot2)
    acc = __builtin_amdgcn_fdot2(wy, m, acc, false);
#else
    acc += (float)wy.x * (float)m.x + (float)wy.y * (float)m.y;
#endif
}

// Wave = 64 consecutive detectors, shear-mapped k; blockIdx.z = k-eighth.
__global__ __launch_bounds__(128) void proj_quad(const uint2* __restrict__ Q,
                                                 const uint2* __restrict__ QT,
                                                 const float* __restrict__ angles,
                                                 float* __restrict__ sino) {
    const int lane = threadIdx.x & 63;
    const int d = blockIdx.x * 128 + (threadIdx.x >> 6) * 64 + lane;
    const int a = blockIdx.y;
    const int z = blockIdx.z;

    float si, co;
    sincosf(angles[a], &si, &co);

    const float cx = (W - 1) * 0.5f, cy = (H - 1) * 0.5f;
    const float s  = (float)d - (ND - 1) * 0.5f;
    const float bx = fmaf(s, co, cx);    // px = bx - t*si
    const float by = fmaf(s, si, cy);    // py = by + t*c

    // Orientation: slow dim = row dim of chosen layout; |sl| >= 0.707.
    const uint2* base;
    float f0, fi, s0, sl, dS;
    if (fabsf(co) >= fabsf(si)) { base = Q;  f0 = bx; fi = -si; s0 = by; sl = co;  dS = si; }
    else                        { base = QT; f0 = by; fi = co;  s0 = bx; sl = -si; dS = co; }

    const float t0 = -(float)(NS - 1) * 0.5f;
    float F0 = fmaf(t0, fi, f0);
    float S0 = fmaf(t0, sl, s0);
    if (sl < 0.f) {   // make slow step positive (reverses sum order only)
        F0 = fmaf((float)(NS - 1), fi, F0); fi = -fi;
        S0 = fmaf((float)(NS - 1), sl, S0); sl = -sl;
    }

    // Outer valid k range (1e-4 margin; clamp handles boundary rounding).
    float kloF, khiF, kloS, khiS;
    range1(F0, fi, -0.9999f, 511.9999f, kloF, khiF);
    range1(S0, sl, -0.9999f, 511.9999f, kloS, khiS);
    const int kA = max(0,      (int)ceilf(fmaxf(kloF, kloS)));
    const int kB = min(NS - 1, (int)floorf(fminf(khiF, khiS)));

    // Interior k range (1e-3 margin): clamp-free evaluation provably safe —
    // shifted coords stay > 0 and floor() <= 512, addresses inside the
    // written quad region, values exact (boundary shells excluded here and
    // handled by the clamped head/tail).
    float iloF, ihiF, iloS, ihiS;
    range1(F0, fi, -0.999f, 511.999f, iloF, ihiF);
    range1(S0, sl, -0.999f, 511.999f, iloS, ihiS);
    const int kAI = max(0,      (int)ceilf(fmaxf(iloF, iloS)));
    const int kBI = min(NS - 1, (int)floorf(fminf(ihiF, ihiS)));

    // Shear offset: aligns slow coords across lanes at fixed loop index j.
    const int o = (int)rintf(-(float)lane * dS / sl);
    // +1 shift folds the pad-ring offset into the clamp domain [0, 513].
    const float F1 = fmaf((float)o, fi, F0) + 1.f;
    const float S1 = fmaf((float)o, sl, S0) + 1.f;

    int jA, jB, iA, iB;
    if (kA <= kB) { jA = kA - o; jB = kB - o; }
    else          { jA = INT_MAX; jB = INT_MIN; }
    // Lanes with empty outer OR empty interior veto the wave interior
    // (they must never run unclamped with garbage coords).
    if (kA <= kB && kAI <= kBI) { iA = kAI - o; iB = kBI - o; }
    else                        { iA = INT_MAX; iB = INT_MIN; }

    int Jlo = jA, Jhi = jB, Ilo = iA, Ihi = iB;
    #pragma unroll
    for (int off = 1; off < 64; off <<= 1) {
        Jlo = min(Jlo, __shfl_xor(Jlo, off));   // union
        Jhi = max(Jhi, __shfl_xor(Jhi, off));
        Ilo = max(Ilo, __shfl_xor(Ilo, off));   // intersection
        Ihi = min(Ihi, __shfl_xor(Ihi, off));
    }
    if (Jlo > Jhi) return;                 // whole wave empty
    const int L  = Jhi - Jlo + 1;
    // Wave-uniform chunk bounds -> scalar registers for scalar loop control.
    const int js = __builtin_amdgcn_readfirstlane(Jlo + (L * z) / KSPLIT);
    const int je = __builtin_amdgcn_readfirstlane(Jlo + (L * (z + 1)) / KSPLIT - 1);
    if (js > je) return;                   // tiny L: empty chunk

    // Interior of this chunk; ragged parts go to clamped scalar loops.
    const int IAw = __builtin_amdgcn_readfirstlane(Ilo);
    const int IBw = __builtin_amdgcn_readfirstlane(Ihi);
    const int isI = max(js, IAw);
    const int ieI = min(je, IBw);
    int p0, nP2;
    if (isI <= ieI) { p0 = isI;    nP2 = (ieI - isI + 1) & ~1; }
    else            { p0 = je + 1; nP2 = 0; }   // no interior: head covers all

    float acc0 = 0.f, acc1 = 0.f;

    // Head: [js, p0-1], clamped (masks lanes not yet in their own range).
    for (int j = js; j < p0; ++j) samp_clamped(base, F1, S1, fi, sl, j, acc0);

    // Interior: [p0, p0+nP2-1], clamp-free 2-sample packed, unroll 4.
    if (nP2 > 0) {
        const f2 fiv = {fi, fi}, slv = {sl, sl};
        const f2 F1v = {F1, F1}, S1v = {S1, S1};
        const f2 c520 = {520.f, 520.f};
        f2 jf2 = {(float)p0, (float)(p0 + 1)};
        #pragma unroll 4
        for (int j = p0; j < p0 + nP2; j += 2) {
            f2 pf = jf2 * fiv + F1v;           // v_pk_fma_f32
            f2 ps = jf2 * slv + S1v;
            jf2 += (f2)2.f;                    // exact (integers)
            const f2 ff = {__builtin_floorf(pf.x), __builtin_floorf(pf.y)};
            const f2 sf = {__builtin_floorf(ps.x), __builtin_floorf(ps.y)};
            const f2 fx = pf - ff;
            const f2 fy = ps - sf;
            const f2 gy = (f2)1.f - fy;
            const f2 aif = sf * c520 + ff;     // exact (< 2^24), >= 0
            const unsigned a0 = (unsigned)aif.x;
            const unsigned a1 = (unsigned)aif.y;
            const uint2 q0 = base[a0];
            const uint2 q1 = base[a1];
            const h2 fxh = __builtin_amdgcn_cvt_pkrtz(fx.x, fx.y);  // one cvt/pair
            {
                const h2 l   = __builtin_bit_cast(h2, q0.x);
                const h2 dl  = __builtin_bit_cast(h2, q0.y);
                const h2 fxx = {fxh.x, fxh.x};                      // op_sel bcast
                const h2 m   = fxx * dl + l;
                const h2 wy  = __builtin_amdgcn_cvt_pkrtz(gy.x, fy.x);
#if __has_builtin(__builtin_amdgcn_fdot2)
                acc0 = __builtin_amdgcn_fdot2(wy, m, acc0, false);
#else
                acc0 += (float)wy.x * (float)m.x + (float)wy.y * (float)m.y;
#endif
            }
            {
                const h2 l   = __builtin_bit_cast(h2, q1.x);
                const h2 dl  = __builtin_bit_cast(h2, q1.y);
                const h2 fxx = {fxh.y, fxh.y};
                const h2 m   = fxx * dl + l;
                const h2 wy  = __builtin_amdgcn_cvt_pkrtz(gy.y, fy.y);
#if __has_builtin(__builtin_amdgcn_fdot2)
                acc1 = __builtin_amdgcn_fdot2(wy, m, acc1, false);
#else
                acc1 += (float)wy.x * (float)m.x + (float)wy.y * (float)m.y;
#endif
            }
        }
    }

    // Tail: [p0+nP2, je] — interior odd sample + past-intersection part.
    for (int j = p0 + nP2; j <= je; ++j) samp_clamped(base, F1, S1, fi, sl, j, acc1);

    const float acc = acc0 + acc1;
    if (d < ND)
        __hip_atomic_fetch_add(&sino[a * ND + d], acc,
                               __ATOMIC_RELAXED, __HIP_MEMORY_SCOPE_AGENT);
}

// ================= fallback (tiny ws): fused fp32 ==========================
__global__ __launch_bounds__(256) void proj_fused(const float* __restrict__ A,
                                                  const float* __restrict__ B,
                                                  const float* __restrict__ angles,
                                                  float* __restrict__ sino) {
    const int d = blockIdx.x * blockDim.x + threadIdx.x;
    const int a = blockIdx.y;
    if (d >= ND) return;
    float si, c;
    sincosf(angles[a], &si, &c);
    const float cx = (W - 1) * 0.5f, cy = (H - 1) * 0.5f;
    const float s  = (float)d - (ND - 1) * 0.5f;
    const float bx = fmaf(s, c, cx), by = fmaf(s, si, cy);
    const float t0 = -(float)(NS - 1) * 0.5f;
    float acc = 0.f;
    for (int k = 0; k < NS; ++k) {
        const float t = t0 + (float)k;
        const float px = fmaf(t, -si, bx), py = fmaf(t, c, by);
        const float x0f = floorf(px), y0f = floorf(py);
        const float fx = px - x0f, fy = py - y0f;
        const int ix = (int)x0f, iy = (int)y0f;
        auto tap = [&](int yi, int xi) -> float {
            if (xi < 0 || xi >= W || yi < 0 || yi >= H) return 0.f;
            return A[yi * W + xi] + B[yi * W + xi];
        };
        float v = 0.f;
        if (ix >= -1 && iy >= -1 && ix <= W - 1 && iy <= H - 1) {
            const float v00 = tap(iy, ix),     v01 = tap(iy, ix + 1);
            const float v10 = tap(iy + 1, ix), v11 = tap(iy + 1, ix + 1);
            const float top = fmaf(fx, v01 - v00, v00);
            const float bot = fmaf(fx, v11 - v10, v10);
            v = fmaf(fy, bot - top, top);
        }
        acc += v;
    }
    sino[a * ND + d] = acc;
}

__global__ void prep_copy(const float* __restrict__ reco, float* __restrict__ reco_out) {
    int i = blockIdx.x * blockDim.x + threadIdx.x;
    if (i < IMG_SIZE) reco_out[i] = reco[i];
}

extern "C" void kernel_launch(void* const* d_in, const int* in_sizes, int n_in,
                              void* d_out, int out_size, void* d_ws, size_t ws_size,
                              hipStream_t stream) {
    const float* x      = (const float*)d_in[0];
    const float* reco   = (const float*)d_in[1];
    const float* angles = (const float*)d_in[2];
    float* sino     = (float*)d_out;
    float* reco_out = sino + SINO_SIZE;

    const size_t need_quads = 2 * (size_t)QUAD_SIZE * sizeof(uint2);    // ~4.28 MiB

    if (ws_size >= need_quads) {
        uint2* Q  = (uint2*)d_ws;
        uint2* QT = Q + QUAD_SIZE;
        prep_quads<<<dim3(17, 17, 4), dim3(32, 8), 0, stream>>>(x, reco, Q, QT, reco_out, sino);
        proj_quad<<<dim3(6, NA, KSPLIT), dim3(128), 0, stream>>>(Q, QT, angles, sino);
    } else {
        prep_copy<<<dim3((IMG_SIZE + 255) / 256), dim3(256), 0, stream>>>(reco, reco_out);
        proj_fused<<<dim3((ND + 255) / 256, NA), dim3(256), 0, stream>>>(x, reco, angles, sino);
    }
}

// Round 2
// 146.432 us; speedup vs baseline: 1.0978x; 1.0978x over previous
//
#include <hip/hip_runtime.h>
#include <hip/hip_fp16.h>
#include <climits>

// Radon forward projection (parallel beam), 512x512 image, 512 angles,
// 736 detectors x 736 samples, bilinear interpolation.
// Outputs (flat, concatenated): sino [1,512,736] then reco [1,512,512].
//
// R14: fix R13's regression. R13's wave-intersection interior was vetoed by
//      lanes whose ray misses the image entirely (INT_MAX veto) -> ~25% of
//      waves (image-edge waves, every angle) fell back to a fully SCALAR
//      clamped loop (slower than R12's packed-clamped; VALUBusy 82->72).
//      Fix 1: dead lanes are neutralized (fi=sl=0, F1=S1=1 -> constant safe
//      coords; acc zero-masked at end) so they run the unclamped interior
//      harmlessly and never veto. Fix 2: head/tail are packed-clamped
//      (template<CLAMP> pair loop = R12 body), never scalar. Keeps R13's
//      delta-quads (r-l precomputed in prep) + single fx cvt per pair.
//      Interior pair = 58 cy vs clamped 74 cy.

namespace {
constexpr int H = 512, W = 512, NA = 512, ND = 736, NS = 736;
constexpr int SINO_SIZE = NA * ND;
constexpr int IMG_SIZE = H * W;
// Quad array: entry (ri,ci), ri,ci in [0,513]:
//   q.x = (v(ri-1,ci-1), v(ri,ci-1))       column pair at ci-1  ("l")
//   q.y = (v(ri-1,ci)-v(ri-1,ci-1),
//          v(ri,ci)  -v(ri,ci-1))          delta pair ("r-l"), f32-computed
// zero outside [0,512)^2. Sample coords shifted +1 -> clamp domain [0,513].
constexpr int QN = 514;
constexpr int QS = 520;                 // row stride in quads (8 B each)
constexpr int QUAD_SIZE = QN * QS;
constexpr int KSPLIT = 8;
}

typedef __fp16 h2 __attribute__((ext_vector_type(2)));
typedef float  f2 __attribute__((ext_vector_type(2)));

// ---------- prep: quads + reco + sino zero; grid (17,17,4), block 32x8 -----
__global__ __launch_bounds__(256) void prep_quads(const float* __restrict__ x,
                                                  const float* __restrict__ reco,
                                                  uint2* __restrict__ Q,
                                                  uint2* __restrict__ QT,
                                                  float* __restrict__ reco_out,
                                                  float* __restrict__ sino) {
    __shared__ float tile[34][35];
    const int tx = threadIdx.x, ty = threadIdx.y;      // 32x8
    const int r0 = blockIdx.y * 32, c0 = blockIdx.x * 32;
    const int z  = blockIdx.z;

    // Zero sinogram (z==0 slice only; d_out is poisoned before every call).
    if (z == 0) {
        const int nthr = 289 * 256;
        const int gtid = (blockIdx.y * 17 + blockIdx.x) * 256 + ty * 32 + tx;
        for (int i = gtid; i < SINO_SIZE; i += nthr) sino[i] = 0.f;
    }

    // Load 34x34 halo tile: cell (yy,xx) = v(r0-1+yy, c0-1+xx), 0 outside.
    for (int li = ty * 32 + tx; li < 34 * 34; li += 256) {
        const int yy = li / 34, xx = li - yy * 34;
        const int r = r0 - 1 + yy, c = c0 - 1 + xx;
        float v = 0.f;
        if ((unsigned)r < 512u && (unsigned)c < 512u) {
            const int i = r * W + c;
            v = x[i] + reco[i];
        }
        tile[yy][xx] = v;
    }
    __syncthreads();

    const int t2 = ty + 8 * z;
    // Q quad: l = column pair at ci-1, delta = (col ci) - (col ci-1)
    const int ri = r0 + t2, ci = c0 + tx;
    if (ri < QN && ci < QN) {
        uint2 q;
        q.x = __builtin_bit_cast(unsigned int,
              __builtin_amdgcn_cvt_pkrtz(tile[t2][tx],     tile[t2 + 1][tx]));
        q.y = __builtin_bit_cast(unsigned int,
              __builtin_amdgcn_cvt_pkrtz(tile[t2][tx + 1]     - tile[t2][tx],
                                         tile[t2 + 1][tx + 1] - tile[t2 + 1][tx]));
        Q[ri * QS + ci] = q;
    }
    // Transposed-image quad at transposed block location.
    const int ri2 = c0 + t2, ci2 = r0 + tx;
    if (ri2 < QN && ci2 < QN) {
        uint2 q;
        q.x = __builtin_bit_cast(unsigned int,
              __builtin_amdgcn_cvt_pkrtz(tile[tx][t2],     tile[tx][t2 + 1]));
        q.y = __builtin_bit_cast(unsigned int,
              __builtin_amdgcn_cvt_pkrtz(tile[tx + 1][t2]     - tile[tx][t2],
                                         tile[tx + 1][t2 + 1] - tile[tx][t2 + 1]));
        QT[ri2 * QS + ci2] = q;
    }
    // reco pass-through (coalesced 4B/lane)
    const int rr = r0 + t2, cc = c0 + tx;
    if (rr < H && cc < W) reco_out[rr * W + cc] = reco[rr * W + cc];
}

// Per-dim k-range for p0 + k*inc in [lo, hi].
__device__ inline void range1(float p0, float inc, float lo, float hi,
                              float& klo, float& khi) {
    if (inc > 1e-6f)       { klo = (lo - p0) / inc; khi = (hi - p0) / inc; }
    else if (inc < -1e-6f) { klo = (hi - p0) / inc; khi = (lo - p0) / inc; }
    else if (p0 >= lo && p0 <= hi) { klo = -1e9f; khi = 1e9f; }
    else                   { klo = 1e9f;  khi = -1e9f; }
}

// Scalar clamped sample (odd-region tails only).
__device__ __forceinline__ void samp_clamped(const uint2* __restrict__ base,
                                             float F1, float S1, float fi, float sl,
                                             int j, float& acc) {
    const float jf = (float)j;
    float pf = fmaf(jf, fi, F1);
    float ps = fmaf(jf, sl, S1);
    pf = fminf(fmaxf(pf, 0.f), 513.f);
    ps = fminf(fmaxf(ps, 0.f), 513.f);
    const float ff = floorf(pf), sf = floorf(ps);
    const float fx = pf - ff,   fy = ps - sf;
    const unsigned ai = (unsigned)fmaf(sf, 520.f, ff);
    const uint2 q = base[ai];
    const h2 l  = __builtin_bit_cast(h2, q.x);
    const h2 dl = __builtin_bit_cast(h2, q.y);          // r - l (prep-computed)
    const h2 fxx = __builtin_amdgcn_cvt_pkrtz(fx, fx);
    const h2 m = fxx * dl + l;
    const h2 wy = __builtin_amdgcn_cvt_pkrtz(1.f - fy, fy);
#if __has_builtin(__builtin_amdgcn_fdot2)
    acc = __builtin_amdgcn_fdot2(wy, m, acc, false);
#else
    acc += (float)wy.x * (float)m.x + (float)wy.y * (float)m.y;
#endif
}

// Packed 2-sample pair loop over inclusive [a, b]; wave-uniform bounds.
// CLAMP=true is the safe path (out-of-own-range samples self-mask to zero
// via the pad ring); CLAMP=false requires every live lane's coords in-range.
template<bool CLAMP>
__device__ __forceinline__ void run_pairs(const uint2* __restrict__ base,
                                          float F1, float S1, float fi, float sl,
                                          int a, int b, float& acc0, float& acc1) {
    const int n = b - a + 1;
    if (n <= 0) return;
    const int e2 = a + (n & ~1) - 1;       // last index of even part
    const f2 fiv = {fi, fi}, slv = {sl, sl};
    const f2 F1v = {F1, F1}, S1v = {S1, S1};
    const f2 c520 = {520.f, 520.f};
    f2 jf2 = {(float)a, (float)(a + 1)};
    #pragma unroll 4
    for (int j = a; j <= e2; j += 2) {
        f2 pf = jf2 * fiv + F1v;           // v_pk_fma_f32
        f2 ps = jf2 * slv + S1v;
        jf2 += (f2)2.f;                    // exact (integers)
        if (CLAMP) {
            pf = __builtin_elementwise_min(__builtin_elementwise_max(pf, (f2)0.f), (f2)513.f);
            ps = __builtin_elementwise_min(__builtin_elementwise_max(ps, (f2)0.f), (f2)513.f);
        }
        const f2 ff = {__builtin_floorf(pf.x), __builtin_floorf(pf.y)};
        const f2 sf = {__builtin_floorf(ps.x), __builtin_floorf(ps.y)};
        const f2 fx = pf - ff;
        const f2 fy = ps - sf;
        const f2 gy = (f2)1.f - fy;
        const f2 aif = sf * c520 + ff;     // exact (< 2^24), >= 0
        const unsigned a0 = (unsigned)aif.x;
        const unsigned a1 = (unsigned)aif.y;
        const uint2 q0 = base[a0];
        const uint2 q1 = base[a1];
        const h2 fxh = __builtin_amdgcn_cvt_pkrtz(fx.x, fx.y);  // one cvt/pair
        {
            const h2 l   = __builtin_bit_cast(h2, q0.x);
            const h2 dl  = __builtin_bit_cast(h2, q0.y);
            const h2 fxx = {fxh.x, fxh.x};                      // op_sel bcast
            const h2 m   = fxx * dl + l;
            const h2 wy  = __builtin_amdgcn_cvt_pkrtz(gy.x, fy.x);
#if __has_builtin(__builtin_amdgcn_fdot2)
            acc0 = __builtin_amdgcn_fdot2(wy, m, acc0, false);
#else
            acc0 += (float)wy.x * (float)m.x + (float)wy.y * (float)m.y;
#endif
        }
        {
            const h2 l   = __builtin_bit_cast(h2, q1.x);
            const h2 dl  = __builtin_bit_cast(h2, q1.y);
            const h2 fxx = {fxh.y, fxh.y};
            const h2 m   = fxx * dl + l;
            const h2 wy  = __builtin_amdgcn_cvt_pkrtz(gy.y, fy.y);
#if __has_builtin(__builtin_amdgcn_fdot2)
            acc1 = __builtin_amdgcn_fdot2(wy, m, acc1, false);
#else
            acc1 += (float)wy.x * (float)m.x + (float)wy.y * (float)m.y;
#endif
        }
    }
    if (n & 1)   // single scalar tail at b; clamped is always safe here
        samp_clamped(base, F1, S1, fi, sl, b, acc1);
}

// Wave = 64 consecutive detectors, shear-mapped k; blockIdx.z = k-eighth.
__global__ __launch_bounds__(128) void proj_quad(const uint2* __restrict__ Q,
                                                 const uint2* __restrict__ QT,
                                                 const float* __restrict__ angles,
                                                 float* __restrict__ sino) {
    const int lane = threadIdx.x & 63;
    const int d = blockIdx.x * 128 + (threadIdx.x >> 6) * 64 + lane;
    const int a = blockIdx.y;
    const int z = blockIdx.z;

    float si, co;
    sincosf(angles[a], &si, &co);

    const float cx = (W - 1) * 0.5f, cy = (H - 1) * 0.5f;
    const float s  = (float)d - (ND - 1) * 0.5f;
    const float bx = fmaf(s, co, cx);    // px = bx - t*si
    const float by = fmaf(s, si, cy);    // py = by + t*c

    // Orientation: slow dim = row dim of chosen layout; |sl| >= 0.707.
    const uint2* base;
    float f0, fi, s0, sl, dS;
    if (fabsf(co) >= fabsf(si)) { base = Q;  f0 = bx; fi = -si; s0 = by; sl = co;  dS = si; }
    else                        { base = QT; f0 = by; fi = co;  s0 = bx; sl = -si; dS = co; }

    const float t0 = -(float)(NS - 1) * 0.5f;
    float F0 = fmaf(t0, fi, f0);
    float S0 = fmaf(t0, sl, s0);
    if (sl < 0.f) {   // make slow step positive (reverses sum order only)
        F0 = fmaf((float)(NS - 1), fi, F0); fi = -fi;
        S0 = fmaf((float)(NS - 1), sl, S0); sl = -sl;
    }

    // Outer valid k range (1e-4 margin; clamp handles boundary rounding).
    float kloF, khiF, kloS, khiS;
    range1(F0, fi, -0.9999f, 511.9999f, kloF, khiF);
    range1(S0, sl, -0.9999f, 511.9999f, kloS, khiS);
    const int kA = max(0,      (int)ceilf(fmaxf(kloF, kloS)));
    const int kB = min(NS - 1, (int)floorf(fminf(khiF, khiS)));

    // Interior k range (1e-3 margin): clamp-free evaluation provably safe —
    // shifted coords stay > 0 and floor() <= 512, addresses inside the
    // written quad region (boundary shells go to the clamped head/tail).
    float iloF, ihiF, iloS, ihiS;
    range1(F0, fi, -0.999f, 511.999f, iloF, ihiF);
    range1(S0, sl, -0.999f, 511.999f, iloS, ihiS);
    const int kAI = max(0,      (int)ceilf(fmaxf(iloF, iloS)));
    const int kBI = min(NS - 1, (int)floorf(fminf(ihiF, ihiS)));

    // Shear offset: aligns slow coords across lanes at fixed loop index j.
    // (sl >= 0.707 always, incl. dead lanes -- computed before overwrite.)
    const int o = (int)rintf(-(float)lane * dS / sl);
    // +1 shift folds the pad-ring offset into the clamp domain [0, 513].
    float F1 = fmaf((float)o, fi, F0) + 1.f;
    float S1 = fmaf((float)o, sl, S0) + 1.f;

    // Dead lane = ray misses the image: neutralize instead of vetoing the
    // wave interior. Constant coords (1,1) are safe unclamped; acc masked 0.
    const bool dead = (kA > kB);
    if (dead) { fi = 0.f; sl = 0.f; F1 = 1.f; S1 = 1.f; }

    int jA, jB, iA, iB;
    if (!dead) { jA = kA - o; jB = kB - o; }
    else       { jA = INT_MAX; jB = INT_MIN; }     // no union extension
    if (dead)            { iA = INT_MIN; iB = INT_MAX; }  // no intersection shrink
    else if (kAI <= kBI) { iA = kAI - o; iB = kBI - o; }
    else                 { iA = INT_MAX; iB = INT_MIN; }  // live, no interior: veto

    int Jlo = jA, Jhi = jB, Ilo = iA, Ihi = iB;
    #pragma unroll
    for (int off = 1; off < 64; off <<= 1) {
        Jlo = min(Jlo, __shfl_xor(Jlo, off));   // union
        Jhi = max(Jhi, __shfl_xor(Jhi, off));
        Ilo = max(Ilo, __shfl_xor(Ilo, off));   // intersection
        Ihi = min(Ihi, __shfl_xor(Ihi, off));
    }
    if (Jlo > Jhi) return;                 // whole wave empty
    const int L  = Jhi - Jlo + 1;
    // Wave-uniform chunk bounds -> scalar registers for scalar loop control.
    const int js = __builtin_amdgcn_readfirstlane(Jlo + (L * z) / KSPLIT);
    const int je = __builtin_amdgcn_readfirstlane(Jlo + (L * (z + 1)) / KSPLIT - 1);
    if (js > je) return;                   // tiny L: empty chunk

    // Interior of this chunk (wave-uniform); empty -> all head (clamped).
    const int IAw = __builtin_amdgcn_readfirstlane(Ilo);
    const int IBw = __builtin_amdgcn_readfirstlane(Ihi);
    int isI = max(js, IAw), ieI = min(je, IBw);
    if (isI > ieI) { isI = je + 1; ieI = je; }

    float acc0 = 0.f, acc1 = 0.f;
    // Head [js, isI-1]: packed clamped (self-masks out-of-own-range lanes).
    run_pairs<true >(base, F1, S1, fi, sl, js, isI - 1, acc0, acc1);
    // Interior [isI, ieI]: packed clamp-free (every live lane in-range).
    run_pairs<false>(base, F1, S1, fi, sl, isI, ieI, acc0, acc1);
    // Tail [ieI+1, je]: packed clamped.
    run_pairs<true >(base, F1, S1, fi, sl, ieI + 1, je, acc0, acc1);

    const float acc = dead ? 0.f : (acc0 + acc1);
    if (d < ND)
        __hip_atomic_fetch_add(&sino[a * ND + d], acc,
                               __ATOMIC_RELAXED, __HIP_MEMORY_SCOPE_AGENT);
}

// ================= fallback (tiny ws): fused fp32 ==========================
__global__ __launch_bounds__(256) void proj_fused(const float* __restrict__ A,
                                                  const float* __restrict__ B,
                                                  const float* __restrict__ angles,
                                                  float* __restrict__ sino) {
    const int d = blockIdx.x * blockDim.x + threadIdx.x;
    const int a = blockIdx.y;
    if (d >= ND) return;
    float si, c;
    sincosf(angles[a], &si, &c);
    const float cx = (W - 1) * 0.5f, cy = (H - 1) * 0.5f;
    const float s  = (float)d - (ND - 1) * 0.5f;
    const float bx = fmaf(s, c, cx), by = fmaf(s, si, cy);
    const float t0 = -(float)(NS - 1) * 0.5f;
    float acc = 0.f;
    for (int k = 0; k < NS; ++k) {
        const float t = t0 + (float)k;
        const float px = fmaf(t, -si, bx), py = fmaf(t, c, by);
        const float x0f = floorf(px), y0f = floorf(py);
        const float fx = px - x0f, fy = py - y0f;
        const int ix = (int)x0f, iy = (int)y0f;
        auto tap = [&](int yi, int xi) -> float {
            if (xi < 0 || xi >= W || yi < 0 || yi >= H) return 0.f;
            return A[yi * W + xi] + B[yi * W + xi];
        };
        float v = 0.f;
        if (ix >= -1 && iy >= -1 && ix <= W - 1 && iy <= H - 1) {
            const float v00 = tap(iy, ix),     v01 = tap(iy, ix + 1);
            const float v10 = tap(iy + 1, ix), v11 = tap(iy + 1, ix + 1);
            const float top = fmaf(fx, v01 - v00, v00);
            const float bot = fmaf(fx, v11 - v10, v10);
            v = fmaf(fy, bot - top, top);
        }
        acc += v;
    }
    sino[a * ND + d] = acc;
}

__global__ void prep_copy(const float* __restrict__ reco, float* __restrict__ reco_out) {
    int i = blockIdx.x * blockDim.x + threadIdx.x;
    if (i < IMG_SIZE) reco_out[i] = reco[i];
}

extern "C" void kernel_launch(void* const* d_in, const int* in_sizes, int n_in,
                              void* d_out, int out_size, void* d_ws, size_t ws_size,
                              hipStream_t stream) {
    const float* x      = (const float*)d_in[0];
    const float* reco   = (const float*)d_in[1];
    const float* angles = (const float*)d_in[2];
    float* sino     = (float*)d_out;
    float* reco_out = sino + SINO_SIZE;

    const size_t need_quads = 2 * (size_t)QUAD_SIZE * sizeof(uint2);    // ~4.28 MiB

    if (ws_size >= need_quads) {
        uint2* Q  = (uint2*)d_ws;
        uint2* QT = Q + QUAD_SIZE;
        prep_quads<<<dim3(17, 17, 4), dim3(32, 8), 0, stream>>>(x, reco, Q, QT, reco_out, sino);
        proj_quad<<<dim3(6, NA, KSPLIT), dim3(128), 0, stream>>>(Q, QT, angles, sino);
    } else {
        prep_copy<<<dim3((IMG_SIZE + 255) / 256), dim3(256), 0, stream>>>(reco, reco_out);
        proj_fused<<<dim3((ND + 255) / 256, NA), dim3(256), 0, stream>>>(x, reco, angles, sino);
    }
}